// Round 1
// baseline (8169.811 us; speedup 1.0000x reference)
//
#include <hip/hip_runtime.h>

#define ALPHA 0.9f
#define THRESH 1.0f
#define BATCH 512
#define CIN 16
#define TSTEPS 2000
#define NRES 1024
#define NCLS 10

#define NGROUP 32       // 32 logical groups of 16 batch rows (mask namespace unchanged)
#define NPAIR 16        // one block owns a PAIR of groups (32 batch rows)
#define BPG 8           // blocks per pair, 128 neurons each -> 128 blocks total

typedef int   v4i __attribute__((ext_vector_type(4)));
typedef float v4f __attribute__((ext_vector_type(4)));
typedef short v8s __attribute__((ext_vector_type(8)));

// ---- ws layout (bytes) ----
#define SLOTC_OFF  8192     // max|W_clf| bits
#define ROWMAX_OFF 9216     // per-row max|W_res[n][:]|, 1024 floats
#define MASK_OFF   16384    // tagged masks: 2 par x 32 g x 16 b x 64 prod x 4 B = 256 KB
#define WQF_OFF    278528   // W_res int8, MFMA-fragment order: 1 MB
#define WCF_OFF    1327104  // W_clf int8 fragment tile: 16 KB
#define LDS_BYTES  (131072 + 16*1040 + 2048 + 8192)  // B slice + A + xA(x2 groups) + redC

__global__ __launch_bounds__(256) void maxabs_kernel(const float* __restrict__ W,
                                                     int n, unsigned* __restrict__ slot) {
    unsigned m = 0u;
    for (int i = blockIdx.x * 256 + threadIdx.x; i < n; i += gridDim.x * 256)
        m = max(m, __float_as_uint(W[i]) & 0x7fffffffu);
#pragma unroll
    for (int off = 32; off >= 1; off >>= 1)
        m = max(m, (unsigned)__shfl_xor((int)m, off, 64));
    if ((threadIdx.x & 63) == 0) atomicMax(slot, m);
}

// per-row max|W_res[n][:]| — one wave per row, plain store (deterministic)
__global__ __launch_bounds__(256) void rowmax_kernel(const float* __restrict__ W,
                                                     float* __restrict__ rowmax) {
    const int row = blockIdx.x * 4 + ((int)threadIdx.x >> 6);
    const int lane = threadIdx.x & 63;
    float m = 0.f;
    for (int j = lane; j < NRES; j += 64) m = fmaxf(m, fabsf(W[row * NRES + j]));
#pragma unroll
    for (int off = 32; off >= 1; off >>= 1) m = fmaxf(m, __shfl_xor(m, off, 64));
    if (lane == 0) rowmax[row] = m;
}

// W_res -> signed-int8 (PER-ROW scale) in MFMA B-fragment order:
// dword o4: bl=o4>>15, wv=(o4>>12)&7, kt=(o4>>8)&15, L=(o4>>2)&63, i0=(o4&3)*4
// n = bl*128+wv*16+(L&15); k = kt*64+(L>>4)*16+i0..+3
__global__ __launch_bounds__(256) void quant_res(const float* __restrict__ W,
                                                 const float* __restrict__ rowmax,
                                                 unsigned* __restrict__ dst) {
    const int o4 = blockIdx.x * 256 + threadIdx.x;
    const int bl = o4 >> 15, wv = (o4 >> 12) & 7, kt = (o4 >> 8) & 15;
    const int L = (o4 >> 2) & 63, i0 = (o4 & 3) * 4;
    const int n = bl * 128 + wv * 16 + (L & 15);
    const int k = kt * 64 + (L >> 4) * 16 + i0;
    const float inv = 127.0f / rowmax[n];
    unsigned dw = 0;
#pragma unroll
    for (int j = 0; j < 4; ++j) {
        float q = rintf(W[n * NRES + k + j] * inv);
        q = fminf(fmaxf(q, -127.f), 127.f);
        dw |= ((unsigned)((int)q & 0xff)) << (8 * j);
    }
    dst[o4] = dw;
}

// W_clf -> int8 fragment tile (16 cols, cls>=10 zero): 4096 dwords
__global__ __launch_bounds__(256) void quant_clf(const float* __restrict__ W,
                                                 const unsigned* __restrict__ slot,
                                                 unsigned* __restrict__ dst) {
    const int o4 = blockIdx.x * 256 + threadIdx.x;
    const int kt = (o4 >> 8) & 15, L = (o4 >> 2) & 63, i0 = (o4 & 3) * 4;
    const int cls = L & 15;
    const int k = kt * 64 + (L >> 4) * 16 + i0;
    const float inv = 127.0f / __uint_as_float(*slot);
    unsigned dw = 0;
    if (cls < NCLS) {
#pragma unroll
        for (int j = 0; j < 4; ++j) {
            float q = rintf(W[cls * NRES + k + j] * inv);
            q = fminf(fmaxf(q, -127.f), 127.f);
            dw |= ((unsigned)((int)q & 0xff)) << (8 * j);
        }
    }
    dst[o4] = dw;
}

__device__ __forceinline__ unsigned short f2bf(float f) {
    unsigned u = __float_as_uint(f);
    return (unsigned short)((u + 0x7fffu + ((u >> 16) & 1u)) >> 16);
}

// tag-validated poll: first check uses the prefetched value (zero-latency on hit)
__device__ __forceinline__ unsigned checkpoll(unsigned long long pf,
        const unsigned long long* mp, unsigned want) {
    unsigned lo = (unsigned)pf, hi = (unsigned)(pf >> 32);
    while (((lo >> 16) != want) | ((hi >> 16) != want)) {
        __builtin_amdgcn_s_sleep(1);
        const unsigned long long u =
            __hip_atomic_load(mp, __ATOMIC_RELAXED, __HIP_MEMORY_SCOPE_AGENT);
        lo = (unsigned)u; hi = (unsigned)(u >> 32);
    }
    return (lo & 0xffffu) | ((hi & 0xffffu) << 16);
}

// 32 spike bits -> 32 int8 {0,1} bytes in A_lds (carry-free nibble spread:
// x*0x00204081 places bits at 0/8/16/24; shifts 0,7,14,21 never overlap for x<16)
__device__ __forceinline__ void expand_masks(unsigned m, char* A_lds, int mb, int mseg) {
    unsigned w[8];
#pragma unroll
    for (int d = 0; d < 8; ++d)
        w[d] = (((m >> (4 * d)) & 15u) * 0x00204081u) & 0x01010101u;
    v4i* dst = (v4i*)(A_lds + mb * 1040 + mseg * 32);
    dst[0] = *(v4i*)&w[0];
    dst[1] = *(v4i*)&w[4];
}

// ---------------------------------------------------------------------------
// DUAL-GROUP PIPELINE: 128 blocks x 512 threads, block = (pair j, slot bl).
// Each block owns TWO independent 16-row batch groups (gA=2j, gB=2j+1) over
// the SAME 128-neuron int8 W slice (LDS-resident once). Per step, phase A
// computes gA while gB's masks are in flight, then phase B computes gB while
// gA's next-step masks are in flight -> the agent-scope store->load fabric
// round trip (the old ~65% stall) is hidden under a full phase of MFMA work.
// Poll loads are additionally PREFETCHED one phase early (tag-checked later,
// retry loop on miss). Numerics identical to the verified single-group kernel
// (same quantization, same MFMA order per group).
// ---------------------------------------------------------------------------
__global__ __launch_bounds__(512, 1) void reservoir_mfma(
    const float* __restrict__ x, const float* __restrict__ W_in,
    unsigned char* __restrict__ ws, float* __restrict__ out)
{
    // XCD co-location heuristic: 8 blocks of pair j share q&7 (round-robin q%8).
    const int q   = (int)blockIdx.x;
    const int j   = ((q >> 3) & 1) * 8 + (q & 7);   // pair 0..15
    const int bl  = q >> 4;                          // 0..7
    const int gA  = 2 * j, gB = 2 * j + 1;
    const int tid = (int)threadIdx.x;
    const int L    = tid & 63;
    const int wv   = tid >> 6;     // 0..7
    const int col  = L & 15;       // MFMA n-col (neuron/cls)
    const int rowq = L >> 4;       // batch quad

    extern __shared__ char lds[];
    char* B_lds = lds;                                    // 131072 B
    char* A_lds = lds + 131072;                           // 16 x 1040 B (shared A/B phases)
    unsigned short* xAb = (unsigned short*)(lds + 131072 + 16 * 1040);  // 2 x 16x32 bf16
    char* redC = lds + 131072 + 16 * 1040 + 2048;         // 8 KB clf partials

    const float* rowmax = (const float*)(ws + ROWMAX_OFF);
    const float cscale = __uint_as_float(*(const unsigned*)(ws + SLOTC_OFF)) * (1.0f / 127.0f);
    unsigned char* maskbuf = ws + MASK_OFF;
    const unsigned char* wqf = ws + WQF_OFF;
    const unsigned char* wcf = ws + WCF_OFF;

    const int nn = bl * 128 + wv * 16 + col;             // my output neuron
    const float dscale = rowmax[nn] * (1.0f / 127.0f);
    const bool clfBlk = (bl == 0);

    // ---- load my 128 KB weight slice into LDS (shared by both groups)
    {
        const v4i* src = (const v4i*)(wqf + (size_t)bl * 131072);
        v4i* dst = (v4i*)B_lds;
        for (int i = tid; i < 8192; i += 512) dst[i] = src[i];
    }

    // ---- W_in hi/lo bf16 B-fragments
    v8s binf_h, binf_l;
#pragma unroll
    for (int i = 0; i < 8; ++i) {
        const int c = (rowq * 8 + i) & 15;
        const float w = W_in[nn * CIN + c];
        const unsigned short h = f2bf(w);
        const float wl = w - __uint_as_float((unsigned)h << 16);
        binf_h[i] = (short)h;
        binf_l[i] = (short)f2bf(wl);
    }

    // ---- classifier fragments preloaded to registers (block 0: wave wv owns kt=2wv,2wv+1)
    v4i bcf0 = {0,0,0,0}, bcf1 = {0,0,0,0};
    if (clfBlk) {
        bcf0 = *(const v4i*)(wcf + (2 * wv + 0) * 1024 + L * 16);
        bcf1 = *(const v4i*)(wcf + (2 * wv + 1) * 1024 + L * 16);
    }

    // per-group state
    float vA[4] = {0.f,0.f,0.f,0.f}, vB[4] = {0.f,0.f,0.f,0.f};
    int   accA[4] = {0,0,0,0},       accB[4] = {0,0,0,0};
    float vcA[4] = {0.f,0.f,0.f,0.f}, vcB[4] = {0.f,0.f,0.f,0.f};
    int   acccA[4] = {0,0,0,0},       acccB[4] = {0,0,0,0};

    const int mb = tid >> 5, mseg = tid & 31;   // my mask-poll / A-build slot
#define MPOLL(G, P) ((const unsigned long long*)(maskbuf + \
        (size_t)(((P) * NGROUP + (G)) * 16 + mb) * 256 + mseg * 8))
    const unsigned long long* pA0 = MPOLL(gA, 0);
    const unsigned long long* pA1 = MPOLL(gA, 1);
    const unsigned long long* pB0 = MPOLL(gB, 0);
    const unsigned long long* pB1 = MPOLL(gB, 1);

    // my x element: tid<256 -> gA rows, tid>=256 -> gB rows
    const int xb = (tid >> 4) & 15, xc = tid & 15;
    const size_t xoff = ((size_t)(((tid < 256) ? gA : gB) * 16 + xb) * CIN + xc) * TSTEPS;
    float xval = x[xoff + 0];

    unsigned long long pfA = 0, pfB = 0;

// ---- per-phase macros (static indices only; no runtime-indexed arrays) ----
#define DIN_COMPUTE(DST, XBASE)                                                   \
    {                                                                             \
        const v8s xa = *(const v8s*)((const char*)(XBASE) + col * 64 + rowq * 16);\
        v4f z = {0.f, 0.f, 0.f, 0.f};                                             \
        const v4f D1 = __builtin_amdgcn_mfma_f32_16x16x32_bf16(xa, binf_h, z, 0, 0, 0); \
        DST = __builtin_amdgcn_mfma_f32_16x16x32_bf16(xa, binf_l, D1, 0, 0, 0);   \
    }

#define DREC_COMPUTE(DR)                                                          \
    {                                                                             \
        const char* Bb = B_lds + wv * 16384;                                      \
        const char* Ab = A_lds + col * 1040 + rowq * 16;                          \
        v4i Dr0 = {0,0,0,0}, Dr1 = {0,0,0,0};                                     \
        _Pragma("unroll 4")                                                       \
        for (int kt = 0; kt < 16; kt += 2) {                                      \
            const v4i a0 = *(const v4i*)(Ab + kt * 64);                           \
            const v4i b0 = *(const v4i*)(Bb + kt * 1024 + L * 16);                \
            const v4i a1 = *(const v4i*)(Ab + (kt + 1) * 64);                     \
            const v4i b1 = *(const v4i*)(Bb + (kt + 1) * 1024 + L * 16);          \
            Dr0 = __builtin_amdgcn_mfma_i32_16x16x64_i8(a0, b0, Dr0, 0, 0, 0);    \
            Dr1 = __builtin_amdgcn_mfma_i32_16x16x64_i8(a1, b1, Dr1, 0, 0, 0);    \
        }                                                                         \
        _Pragma("unroll")                                                         \
        for (int r = 0; r < 4; ++r) DR[r] = Dr0[r] + Dr1[r];                      \
    }

#define CLF_PARTIAL                                                               \
    {                                                                             \
        const char* Ab = A_lds + col * 1040 + rowq * 16;                          \
        v4i Dc = {0,0,0,0};                                                       \
        const v4i a0 = *(const v4i*)(Ab + (2 * wv + 0) * 64);                     \
        const v4i a1 = *(const v4i*)(Ab + (2 * wv + 1) * 64);                     \
        Dc = __builtin_amdgcn_mfma_i32_16x16x64_i8(a0, bcf0, Dc, 0, 0, 0);        \
        Dc = __builtin_amdgcn_mfma_i32_16x16x64_i8(a1, bcf1, Dc, 0, 0, 0);        \
        *(v4i*)(redC + wv * 1024 + L * 16) = Dc;                                  \
    }

#define CLF_REDUCE(VC, ACCC)                                                      \
    {                                                                             \
        v4i c0 = *(const v4i*)(redC + 0 * 1024 + L * 16);                         \
        _Pragma("unroll")                                                         \
        for (int jj = 1; jj < 8; ++jj) {                                          \
            const v4i cj = *(const v4i*)(redC + jj * 1024 + L * 16);              \
            _Pragma("unroll")                                                     \
            for (int r = 0; r < 4; ++r) c0[r] += cj[r];                           \
        }                                                                         \
        _Pragma("unroll")                                                         \
        for (int r = 0; r < 4; ++r) {                                             \
            const float vcn = ALPHA * VC[r] + cscale * (float)c0[r];              \
            const int sc = (vcn >= THRESH);                                       \
            ACCC[r] += sc;                                                        \
            VC[r] = sc ? 0.f : vcn;                                              \
        }                                                                         \
    }

// LIF + ballots + early publish (register/global only -> safe before S3)
#define LIF_PUBLISH(V, ACC, DIN, DREC, G, PAR)                                    \
    {                                                                             \
        unsigned long long bal0, bal1, bal2, bal3;                                \
        float vn; int s;                                                          \
        vn = ALPHA * V[0] + DIN[0] + dscale * (float)DREC[0];                     \
        s = (vn >= THRESH); ACC[0] += s; V[0] = s ? 0.f : vn; bal0 = __ballot(s); \
        vn = ALPHA * V[1] + DIN[1] + dscale * (float)DREC[1];                     \
        s = (vn >= THRESH); ACC[1] += s; V[1] = s ? 0.f : vn; bal1 = __ballot(s); \
        vn = ALPHA * V[2] + DIN[2] + dscale * (float)DREC[2];                     \
        s = (vn >= THRESH); ACC[2] += s; V[2] = s ? 0.f : vn; bal2 = __ballot(s); \
        vn = ALPHA * V[3] + DIN[3] + dscale * (float)DREC[3];                     \
        s = (vn >= THRESH); ACC[3] += s; V[3] = s ? 0.f : vn; bal3 = __ballot(s); \
        if (L < 16) {                                                             \
            const unsigned long long bb = (L & 2) ? ((L & 1) ? bal3 : bal2)       \
                                                  : ((L & 1) ? bal1 : bal0);      \
            const unsigned fld = (unsigned)((bb >> ((L >> 2) * 16)) & 0xFFFFu);   \
            unsigned* mp = (unsigned*)(maskbuf +                                  \
                (size_t)(((PAR) * NGROUP + (G)) * 16 + L) * 256 + (bl * 8 + wv) * 4); \
            __hip_atomic_store(mp, ((unsigned)(t + 1) << 16) | fld,               \
                               __ATOMIC_RELAXED, __HIP_MEMORY_SCOPE_AGENT);       \
        }                                                                         \
    }

    __syncthreads();

    for (int t = 0; t < TSTEPS; ++t) {
        const int p  = t & 1;      // publish parity
        const int pp = p ^ 1;      // poll parity ((t-1)&1 for t>=1)

        // ---- stage x_t hi/lo for BOTH groups (writes ordered vs prev step by S3B)
        {
            const unsigned short h = f2bf(xval);
            const float lo2 = xval - __uint_as_float((unsigned)h << 16);
            unsigned short* xr = xAb + ((tid < 256) ? 0 : 512) + xb * 32;
            xr[xc] = h;
            xr[16 + xc] = f2bf(lo2);
        }

        // ================= phase A (group gA) =================
        if (t > 0) {
            const unsigned m = checkpoll(pfA, pp ? pA1 : pA0, (unsigned)t);
            expand_masks(m, A_lds, mb, mseg);
        }
        __syncthreads();   // S2A: A + xA ready

        // prefetch gB's masks for THIS step (published ~1.5 phases ago -> hot)
        if (t > 0)
            pfB = __hip_atomic_load(pp ? pB1 : pB0, __ATOMIC_RELAXED,
                                    __HIP_MEMORY_SCOPE_AGENT);
        // prefetch next step's x (full step of latency hiding)
        float xnext = 0.f;
        if (t + 1 < TSTEPS) xnext = x[xoff + (t + 1)];

        v4f DinA; DIN_COMPUTE(DinA, xAb);
        v4i DrecA = {0, 0, 0, 0};
        if (t > 0) DREC_COMPUTE(DrecA);
        if (clfBlk && t > 0) CLF_PARTIAL;

        LIF_PUBLISH(vA, accA, DinA, DrecA, gA, p);

        __syncthreads();   // S3A: A consumed; redC ready
        if (clfBlk && wv == 0 && t > 0) CLF_REDUCE(vcA, acccA);

        // ================= phase B (group gB) =================
        if (t > 0) {
            const unsigned m = checkpoll(pfB, pp ? pB1 : pB0, (unsigned)t);
            expand_masks(m, A_lds, mb, mseg);
        }
        __syncthreads();   // S2B

        // prefetch gA's masks for step t+1 (published in phase A just above;
        // ~500+ cycles old at issue, checked a full phase later)
        pfA = __hip_atomic_load(p ? pA1 : pA0, __ATOMIC_RELAXED,
                                __HIP_MEMORY_SCOPE_AGENT);

        v4f DinB; DIN_COMPUTE(DinB, xAb + 512);
        v4i DrecB = {0, 0, 0, 0};
        if (t > 0) DREC_COMPUTE(DrecB);
        if (clfBlk && t > 0) CLF_PARTIAL;

        LIF_PUBLISH(vB, accB, DinB, DrecB, gB, p);

        __syncthreads();   // S3B
        if (clfBlk && wv == 0 && t > 0) CLF_REDUCE(vcB, acccB);

        xval = xnext;
    }

    // ---- epilogue: classifier flush with s_{T-1} (parity 1, tag TSTEPS)
    if (clfBlk) {
        {
            const unsigned m = checkpoll(pfA, pA1, (unsigned)TSTEPS);
            expand_masks(m, A_lds, mb, mseg);
        }
        __syncthreads();
        pfB = __hip_atomic_load(pB1, __ATOMIC_RELAXED, __HIP_MEMORY_SCOPE_AGENT);
        CLF_PARTIAL;
        __syncthreads();
        if (wv == 0) {
            v4i c0 = *(const v4i*)(redC + 0 * 1024 + L * 16);
#pragma unroll
            for (int jj = 1; jj < 8; ++jj) {
                const v4i cj = *(const v4i*)(redC + jj * 1024 + L * 16);
#pragma unroll
                for (int r = 0; r < 4; ++r) c0[r] += cj[r];
            }
            if (col < NCLS) {
#pragma unroll
                for (int r = 0; r < 4; ++r) {
                    const float vcn = ALPHA * vcA[r] + cscale * (float)c0[r];
                    const int sc = (vcn >= THRESH);
                    out[(size_t)(gA * 16 + rowq * 4 + r) * NCLS + col] =
                        (float)(acccA[r] + sc);
                }
            }
        }
        {
            const unsigned m = checkpoll(pfB, pB1, (unsigned)TSTEPS);
            expand_masks(m, A_lds, mb, mseg);
        }
        __syncthreads();
        CLF_PARTIAL;
        __syncthreads();
        if (wv == 0) {
            v4i c0 = *(const v4i*)(redC + 0 * 1024 + L * 16);
#pragma unroll
            for (int jj = 1; jj < 8; ++jj) {
                const v4i cj = *(const v4i*)(redC + jj * 1024 + L * 16);
#pragma unroll
                for (int r = 0; r < 4; ++r) c0[r] += cj[r];
            }
            if (col < NCLS) {
#pragma unroll
                for (int r = 0; r < 4; ++r) {
                    const float vcn = ALPHA * vcB[r] + cscale * (float)c0[r];
                    const int sc = (vcn >= THRESH);
                    out[(size_t)(gB * 16 + rowq * 4 + r) * NCLS + col] =
                        (float)(acccB[r] + sc);
                }
            }
        }
    }
    {
#pragma unroll
        for (int r = 0; r < 4; ++r) {
            out[BATCH * NCLS + (size_t)(gA * 16 + rowq * 4 + r) * NRES + nn] = (float)accA[r];
            out[BATCH * NCLS + (size_t)(gB * 16 + rowq * 4 + r) * NRES + nn] = (float)accB[r];
        }
    }
}

extern "C" void kernel_launch(void* const* d_in, const int* in_sizes, int n_in,
                              void* d_out, int out_size, void* d_ws, size_t ws_size,
                              hipStream_t stream) {
    (void)in_sizes; (void)n_in; (void)out_size; (void)ws_size;
    const float* x     = (const float*)d_in[0];
    const float* W_in  = (const float*)d_in[1];
    const float* W_res = (const float*)d_in[2];
    const float* W_clf = (const float*)d_in[3];
    float* out = (float*)d_out;
    unsigned char* ws = (unsigned char*)d_ws;

    // zero: scale slots + rowmax + ENTIRE tagged-mask region (tags 0 never match)
    hipMemsetAsync(ws, 0, MASK_OFF + 262144, stream);
    rowmax_kernel<<<256, 256, 0, stream>>>(W_res, (float*)(ws + ROWMAX_OFF));
    maxabs_kernel<<<16, 256, 0, stream>>>(W_clf, NCLS * NRES, (unsigned*)(ws + SLOTC_OFF));
    quant_res<<<1024, 256, 0, stream>>>(W_res, (const float*)(ws + ROWMAX_OFF),
                                        (unsigned*)(ws + WQF_OFF));
    quant_clf<<<16, 256, 0, stream>>>(W_clf, (const unsigned*)(ws + SLOTC_OFF),
                                      (unsigned*)(ws + WCF_OFF));
    reservoir_mfma<<<NPAIR * BPG, 512, LDS_BYTES, stream>>>(x, W_in, ws, out);
}

// Round 2
// 6711.182 us; speedup vs baseline: 1.2173x; 1.2173x over previous
//
#include <hip/hip_runtime.h>

#define ALPHA 0.9f
#define THRESH 1.0f
#define BATCH 512
#define CIN 16
#define TSTEPS 2000
#define NRES 1024
#define NCLS 10

#define NGROUP 32       // 32 batch groups of 16 rows
#define BPG 8           // blocks per group, 128 neurons each -> 256 blocks

typedef int   v4i __attribute__((ext_vector_type(4)));
typedef float v4f __attribute__((ext_vector_type(4)));
typedef short v8s __attribute__((ext_vector_type(8)));

// ---- ws layout (bytes) ----
#define SLOTC_OFF  8192     // max|W_clf| bits
#define ROWMAX_OFF 9216     // per-row max|W_res[n][:]|, 1024 floats
#define MASK_OFF   16384    // tagged masks: 2 par x 32 g x 16 b x 64 prod x 4 B = 256 KB
#define WQF_OFF    278528   // W_res int8, MFMA-fragment order: 1 MB
#define WCF_OFF    1327104  // W_clf int8 fragment tile: 16 KB
// LDS: A in fragment order (16 kt x 1024 B) + xA (16x32x2 bf16) + redC
#define LDS_BYTES  (16384 + 1024 + 8192)

__global__ __launch_bounds__(256) void maxabs_kernel(const float* __restrict__ W,
                                                     int n, unsigned* __restrict__ slot) {
    unsigned m = 0u;
    for (int i = blockIdx.x * 256 + threadIdx.x; i < n; i += gridDim.x * 256)
        m = max(m, __float_as_uint(W[i]) & 0x7fffffffu);
#pragma unroll
    for (int off = 32; off >= 1; off >>= 1)
        m = max(m, (unsigned)__shfl_xor((int)m, off, 64));
    if ((threadIdx.x & 63) == 0) atomicMax(slot, m);
}

// per-row max|W_res[n][:]| — one wave per row, plain store (deterministic)
__global__ __launch_bounds__(256) void rowmax_kernel(const float* __restrict__ W,
                                                     float* __restrict__ rowmax) {
    const int row = blockIdx.x * 4 + ((int)threadIdx.x >> 6);
    const int lane = threadIdx.x & 63;
    float m = 0.f;
    for (int j = lane; j < NRES; j += 64) m = fmaxf(m, fabsf(W[row * NRES + j]));
#pragma unroll
    for (int off = 32; off >= 1; off >>= 1) m = fmaxf(m, __shfl_xor(m, off, 64));
    if (lane == 0) rowmax[row] = m;
}

// W_res -> signed-int8 (PER-ROW scale) in MFMA B-fragment order:
// dword o4: bl=o4>>15, wv=(o4>>12)&7, kt=(o4>>8)&15, L=(o4>>2)&63, i0=(o4&3)*4
// n = bl*128+wv*16+(L&15); k = kt*64+(L>>4)*16+i0..+3
__global__ __launch_bounds__(256) void quant_res(const float* __restrict__ W,
                                                 const float* __restrict__ rowmax,
                                                 unsigned* __restrict__ dst) {
    const int o4 = blockIdx.x * 256 + threadIdx.x;
    const int bl = o4 >> 15, wv = (o4 >> 12) & 7, kt = (o4 >> 8) & 15;
    const int L = (o4 >> 2) & 63, i0 = (o4 & 3) * 4;
    const int n = bl * 128 + wv * 16 + (L & 15);
    const int k = kt * 64 + (L >> 4) * 16 + i0;
    const float inv = 127.0f / rowmax[n];
    unsigned dw = 0;
#pragma unroll
    for (int j = 0; j < 4; ++j) {
        float q = rintf(W[n * NRES + k + j] * inv);
        q = fminf(fmaxf(q, -127.f), 127.f);
        dw |= ((unsigned)((int)q & 0xff)) << (8 * j);
    }
    dst[o4] = dw;
}

// W_clf -> int8 fragment tile (16 cols, cls>=10 zero): 4096 dwords
__global__ __launch_bounds__(256) void quant_clf(const float* __restrict__ W,
                                                 const unsigned* __restrict__ slot,
                                                 unsigned* __restrict__ dst) {
    const int o4 = blockIdx.x * 256 + threadIdx.x;
    const int kt = (o4 >> 8) & 15, L = (o4 >> 2) & 63, i0 = (o4 & 3) * 4;
    const int cls = L & 15;
    const int k = kt * 64 + (L >> 4) * 16 + i0;
    const float inv = 127.0f / __uint_as_float(*slot);
    unsigned dw = 0;
    if (cls < NCLS) {
#pragma unroll
        for (int j = 0; j < 4; ++j) {
            float q = rintf(W[cls * NRES + k + j] * inv);
            q = fminf(fmaxf(q, -127.f), 127.f);
            dw |= ((unsigned)((int)q & 0xff)) << (8 * j);
        }
    }
    dst[o4] = dw;
}

__device__ __forceinline__ unsigned short f2bf(float f) {
    unsigned u = __float_as_uint(f);
    return (unsigned short)((u + 0x7fffu + ((u >> 16) & 1u)) >> 16);
}

// 32 spike bits -> 32 int8 {0,1} bytes, written in MFMA-fragment order with
// XOR swizzle (slot ^= kt&7) so BOTH the write (this function) and the read
// (kt*1024 + L*16) have unique (128B-row, 16B-slot) per lane -> conflict-free.
// Carry-free nibble spread: x*0x00204081 places bits at 0/8/16/24 for x<16.
__device__ __forceinline__ void expand_masks(unsigned m, char* A_frag, int mb, int mseg) {
    unsigned w[8];
#pragma unroll
    for (int d = 0; d < 8; ++d)
        w[d] = (((m >> (4 * d)) & 15u) * 0x00204081u) & 0x01010101u;
    const int kt = mseg >> 1;
    const int base = kt * 1024 + (mseg & 1) * 512 + mb * 16;
    char* dst = A_frag + (base ^ ((kt & 7) << 4));
    *(v4i*)dst = *(v4i*)&w[0];
    *(v4i*)(dst + 256) = *(v4i*)&w[4];
}

// ---------------------------------------------------------------------------
// 256 blocks x 512 threads (1/CU). Block = (group g, slot bl): 16 batch rows
// x 128 neurons. Inter-block sync = self-validating tagged masks (unchanged
// from the verified 5.14 ms kernel). NEW vs that kernel:
//   (1) W_res B-fragments held in REGISTERS (16 v4i = 64 VGPR/wave), loaded
//       once from global -> -16 ds_read_b128/wave/step (-50% LDS read traffic)
//       and the 128 KB B LDS buffer is gone.
//   (2) A (spike matrix) stored in MFMA-fragment order with XOR swizzle ->
//       conflict-free ds_read_b128/ds_write_b128 (kills the 3.48e8
//       SQ_LDS_BANK_CONFLICT of the stride-1040 layout).
// Numerics bit-identical: same quantization, same MFMA chains/order.
// ---------------------------------------------------------------------------
__global__ __launch_bounds__(512, 1) void reservoir_mfma(
    const float* __restrict__ x, const float* __restrict__ W_in,
    unsigned char* __restrict__ ws, float* __restrict__ out)
{
    // XCD co-location: 8 blocks of a group share q%8 (dispatch heuristic).
    const int q   = (int)blockIdx.x;
    const int g   = (q & 7) * 4 + ((q >> 3) & 3);
    const int bl  = q >> 5;
    const int tid = (int)threadIdx.x;
    const int L    = tid & 63;
    const int wv   = tid >> 6;     // 0..7
    const int col  = L & 15;       // MFMA n-col (neuron/cls)
    const int rowq = L >> 4;       // batch quad
    const int lsw  = L * 16;       // lane offset within a fragment k-tile

    extern __shared__ char lds[];
    char* A_frag = lds;                                   // 16384 B (16 kt x 1024)
    unsigned short* xA = (unsigned short*)(lds + 16384);  // 16x32 bf16
    char* redC = lds + 16384 + 1024;                      // 8 KB clf partials

    const float* rowmax = (const float*)(ws + ROWMAX_OFF);
    const float cscale = __uint_as_float(*(const unsigned*)(ws + SLOTC_OFF)) * (1.0f / 127.0f);
    unsigned char* maskbuf = ws + MASK_OFF;
    const unsigned char* wqf = ws + WQF_OFF;
    const unsigned char* wcf = ws + WCF_OFF;

    const int nn = bl * 128 + wv * 16 + col;             // my output neuron
    const float dscale = rowmax[nn] * (1.0f / 127.0f);
    const bool clfBlk = (bl == 0);

    // ---- W_res B-fragments -> REGISTERS (wave wv: 16 kt x v4i, 64 VGPR)
    v4i brf[16];
    {
        const char* bsrc = (const char*)(wqf + (size_t)bl * 131072 + wv * 16384 + lsw);
#pragma unroll
        for (int kt = 0; kt < 16; ++kt)
            brf[kt] = *(const v4i*)(bsrc + kt * 1024);
    }

    // ---- W_in hi/lo bf16 B-fragments
    v8s binf_h, binf_l;
#pragma unroll
    for (int i = 0; i < 8; ++i) {
        const int c = (rowq * 8 + i) & 15;
        const float w = W_in[nn * CIN + c];
        const unsigned short h = f2bf(w);
        const float wl = w - __uint_as_float((unsigned)h << 16);
        binf_h[i] = (short)h;
        binf_l[i] = (short)f2bf(wl);
    }

    // ---- classifier fragments preloaded to registers (block 0: wave wv owns kt=2wv,2wv+1)
    v4i bcf0 = {0,0,0,0}, bcf1 = {0,0,0,0};
    if (clfBlk) {
        bcf0 = *(const v4i*)(wcf + (2 * wv + 0) * 1024 + L * 16);
        bcf1 = *(const v4i*)(wcf + (2 * wv + 1) * 1024 + L * 16);
    }

    float v[4]  = {0.f, 0.f, 0.f, 0.f};
    int   accv[4] = {0, 0, 0, 0};
    float vc[4] = {0.f, 0.f, 0.f, 0.f};   // live on block0/wave0
    int   accc[4] = {0, 0, 0, 0};

    const int mb = tid >> 5, mseg = tid & 31;   // my mask-poll / A-build slot
    const unsigned long long* mybase0 = (const unsigned long long*)(maskbuf +
        (size_t)((0 * NGROUP + g) * 16 + mb) * 256 + mseg * 8);
    const unsigned long long* mybase1 = (const unsigned long long*)(maskbuf +
        (size_t)((1 * NGROUP + g) * 16 + mb) * 256 + mseg * 8);

    // my x element (tid<256 stage xA); prefetched one step ahead
    const int xb = (tid >> 4) & 15, xc = tid & 15;
    const size_t xoff = (tid < 256)
        ? ((size_t)(g * 16 + xb) * CIN + xc) * TSTEPS : 0;
    float xval = x[xoff];

    __syncthreads();

    for (int t = 0; t < TSTEPS; ++t) {
        if (t > 0) {
            // ---- poll tagged masks of step t-1 (parity (t-1)&1), expand to A
            const unsigned long long* mp = ((t - 1) & 1) ? mybase1 : mybase0;
            const unsigned want = (unsigned)t;
            unsigned lo, hi;
            for (;;) {
                const unsigned long long u =
                    __hip_atomic_load(mp, __ATOMIC_RELAXED, __HIP_MEMORY_SCOPE_AGENT);
                lo = (unsigned)u; hi = (unsigned)(u >> 32);
                if (((lo >> 16) == want) & ((hi >> 16) == want)) break;
                __builtin_amdgcn_s_sleep(1);
            }
            expand_masks((lo & 0xffffu) | ((hi & 0xffffu) << 16), A_frag, mb, mseg);
        }
        // ---- stage x_t hi/lo (safe: all threads passed S3 of step t-1)
        if (tid < 256) {
            const unsigned short h = f2bf(xval);
            const float lo2 = xval - __uint_as_float((unsigned)h << 16);
            xA[xb * 32 + xc] = h;
            xA[xb * 32 + 16 + xc] = f2bf(lo2);
        }
        __syncthreads();   // S2: A + xA ready

        // ---- prefetch next step's x under the MFMA phase
        float xnext = 0.f;
        if (tid < 256 && t + 1 < TSTEPS) xnext = x[xoff + (t + 1)];

        // ---- input projection: (xh+xl).(Wh+Wl), 2 chained bf16 MFMAs
        v4f Din;
        {
            const v8s xa = *(const v8s*)((const char*)xA + col * 64 + rowq * 16);
            v4f z = {0.f, 0.f, 0.f, 0.f};
            const v4f D1 = __builtin_amdgcn_mfma_f32_16x16x32_bf16(xa, binf_h, z, 0, 0, 0);
            Din = __builtin_amdgcn_mfma_f32_16x16x32_bf16(xa, binf_l, D1, 0, 0, 0);
        }

        // ---- recurrent: 16 x mfma_i32_16x16x64_i8, B from registers,
        //      A from swizzled fragment-order LDS (conflict-free)
        v4i Drec = {0, 0, 0, 0};
        if (t > 0) {
            v4i Dr0 = {0,0,0,0}, Dr1 = {0,0,0,0};
#pragma unroll
            for (int kt = 0; kt < 16; kt += 2) {
                const v4i a0 = *(const v4i*)(A_frag + kt * 1024 + (lsw ^ ((kt & 7) << 4)));
                const v4i a1 = *(const v4i*)(A_frag + (kt + 1) * 1024 + (lsw ^ (((kt + 1) & 7) << 4)));
                Dr0 = __builtin_amdgcn_mfma_i32_16x16x64_i8(a0, brf[kt], Dr0, 0, 0, 0);
                Dr1 = __builtin_amdgcn_mfma_i32_16x16x64_i8(a1, brf[kt + 1], Dr1, 0, 0, 0);
            }
#pragma unroll
            for (int r = 0; r < 4; ++r) Drec[r] = Dr0[r] + Dr1[r];
        }

        // ---- classifier partials (block 0, spread: wave wv does kt=2wv,2wv+1)
        if (clfBlk && t > 0) {
            const int k0 = 2 * wv, k1 = 2 * wv + 1;
            v4i Dc = {0, 0, 0, 0};
            const v4i a0 = *(const v4i*)(A_frag + k0 * 1024 + (lsw ^ ((k0 & 7) << 4)));
            const v4i a1 = *(const v4i*)(A_frag + k1 * 1024 + (lsw ^ ((k1 & 7) << 4)));
            Dc = __builtin_amdgcn_mfma_i32_16x16x64_i8(a0, bcf0, Dc, 0, 0, 0);
            Dc = __builtin_amdgcn_mfma_i32_16x16x64_i8(a1, bcf1, Dc, 0, 0, 0);
            *(v4i*)(redC + wv * 1024 + L * 16) = Dc;
        }

        // ---- LIF + spikes + ballots
        unsigned long long bal0, bal1, bal2, bal3;
        {
            float vn; int s;
            vn = ALPHA * v[0] + Din[0] + dscale * (float)Drec[0];
            s = (vn >= THRESH); accv[0] += s; v[0] = s ? 0.f : vn; bal0 = __ballot(s);
            vn = ALPHA * v[1] + Din[1] + dscale * (float)Drec[1];
            s = (vn >= THRESH); accv[1] += s; v[1] = s ? 0.f : vn; bal1 = __ballot(s);
            vn = ALPHA * v[2] + Din[2] + dscale * (float)Drec[2];
            s = (vn >= THRESH); accv[2] += s; v[2] = s ? 0.f : vn; bal2 = __ballot(s);
            vn = ALPHA * v[3] + Din[3] + dscale * (float)Drec[3];
            s = (vn >= THRESH); accv[3] += s; v[3] = s ? 0.f : vn; bal3 = __ballot(s);
        }

        // ---- publish tagged mask dword (tag = t+1), lanes 0..15
        {
            const int p = t & 1;
            if (L < 16) {
                const int b = L;
                const unsigned long long bb = (b & 2) ? ((b & 1) ? bal3 : bal2)
                                                      : ((b & 1) ? bal1 : bal0);
                const unsigned fld = (unsigned)((bb >> ((b >> 2) * 16)) & 0xFFFFu);
                unsigned* mp = (unsigned*)(maskbuf +
                    (size_t)((p * NGROUP + g) * 16 + b) * 256 + (bl * 8 + wv) * 4);
                __hip_atomic_store(mp, ((unsigned)(t + 1) << 16) | fld,
                                   __ATOMIC_RELAXED, __HIP_MEMORY_SCOPE_AGENT);
            }
        }
        __syncthreads();   // S3: A/xA consumed; redC ready

        // ---- classifier reduce + LIF (block 0, wave 0; reads redC after S3)
        if (clfBlk && wv == 0 && t > 0) {
            v4i c0 = *(const v4i*)(redC + 0 * 1024 + L * 16);
#pragma unroll
            for (int jj = 1; jj < 8; ++jj) {
                const v4i cj = *(const v4i*)(redC + jj * 1024 + L * 16);
#pragma unroll
                for (int r = 0; r < 4; ++r) c0[r] += cj[r];
            }
#pragma unroll
            for (int r = 0; r < 4; ++r) {
                const float vcn = ALPHA * vc[r] + cscale * (float)c0[r];
                const int sc = (vcn >= THRESH);
                accc[r] += sc;
                vc[r] = sc ? 0.f : vcn;
            }
        }
        xval = xnext;
        // no end-of-loop barrier: next-step poll gates each thread's A-write;
        // S2/S3 order all LDS hazards (see analysis in session notes).
    }

    // ---- epilogue: classifier flush with s_{T-1} (parity 1, tag TSTEPS)
    if (clfBlk) {
        {
            const unsigned want = (unsigned)TSTEPS;
            unsigned lo, hi;
            for (;;) {
                const unsigned long long u =
                    __hip_atomic_load(mybase1, __ATOMIC_RELAXED, __HIP_MEMORY_SCOPE_AGENT);
                lo = (unsigned)u; hi = (unsigned)(u >> 32);
                if (((lo >> 16) == want) & ((hi >> 16) == want)) break;
                __builtin_amdgcn_s_sleep(1);
            }
            expand_masks((lo & 0xffffu) | ((hi & 0xffffu) << 16), A_frag, mb, mseg);
        }
        __syncthreads();
        {
            const int k0 = 2 * wv, k1 = 2 * wv + 1;
            v4i Dc = {0, 0, 0, 0};
            const v4i a0 = *(const v4i*)(A_frag + k0 * 1024 + (lsw ^ ((k0 & 7) << 4)));
            const v4i a1 = *(const v4i*)(A_frag + k1 * 1024 + (lsw ^ ((k1 & 7) << 4)));
            Dc = __builtin_amdgcn_mfma_i32_16x16x64_i8(a0, bcf0, Dc, 0, 0, 0);
            Dc = __builtin_amdgcn_mfma_i32_16x16x64_i8(a1, bcf1, Dc, 0, 0, 0);
            *(v4i*)(redC + wv * 1024 + L * 16) = Dc;
        }
        __syncthreads();
        if (wv == 0 && col < NCLS) {
            v4i c0 = *(const v4i*)(redC + 0 * 1024 + L * 16);
#pragma unroll
            for (int jj = 1; jj < 8; ++jj) {
                const v4i cj = *(const v4i*)(redC + jj * 1024 + L * 16);
#pragma unroll
                for (int r = 0; r < 4; ++r) c0[r] += cj[r];
            }
#pragma unroll
            for (int r = 0; r < 4; ++r) {
                const float vcn = ALPHA * vc[r] + cscale * (float)c0[r];
                const int sc = (vcn >= THRESH);
                out[(size_t)(g * 16 + rowq * 4 + r) * NCLS + col] = (float)(accc[r] + sc);
            }
        }
    }
    {
#pragma unroll
        for (int r = 0; r < 4; ++r) {
            const int bglob = g * 16 + rowq * 4 + r;
            out[BATCH * NCLS + (size_t)bglob * NRES + nn] = (float)accv[r];
        }
    }
}

extern "C" void kernel_launch(void* const* d_in, const int* in_sizes, int n_in,
                              void* d_out, int out_size, void* d_ws, size_t ws_size,
                              hipStream_t stream) {
    (void)in_sizes; (void)n_in; (void)out_size; (void)ws_size;
    const float* x     = (const float*)d_in[0];
    const float* W_in  = (const float*)d_in[1];
    const float* W_res = (const float*)d_in[2];
    const float* W_clf = (const float*)d_in[3];
    float* out = (float*)d_out;
    unsigned char* ws = (unsigned char*)d_ws;

    // zero: scale slots + rowmax + ENTIRE tagged-mask region (tags 0 never match)
    hipMemsetAsync(ws, 0, MASK_OFF + 262144, stream);
    rowmax_kernel<<<256, 256, 0, stream>>>(W_res, (float*)(ws + ROWMAX_OFF));
    maxabs_kernel<<<16, 256, 0, stream>>>(W_clf, NCLS * NRES, (unsigned*)(ws + SLOTC_OFF));
    quant_res<<<1024, 256, 0, stream>>>(W_res, (const float*)(ws + ROWMAX_OFF),
                                        (unsigned*)(ws + WQF_OFF));
    quant_clf<<<16, 256, 0, stream>>>(W_clf, (const unsigned*)(ws + SLOTC_OFF),
                                      (unsigned*)(ws + WCF_OFF));
    reservoir_mfma<<<NGROUP * BPG, 512, LDS_BYTES, stream>>>(x, W_in, ws, out);
}

// Round 3
// 5454.946 us; speedup vs baseline: 1.4977x; 1.2303x over previous
//
#include <hip/hip_runtime.h>

#define ALPHA 0.9f
#define THRESH 1.0f
#define BATCH 512
#define CIN 16
#define TSTEPS 2000
#define NRES 1024
#define NCLS 10

#define NGROUP 32       // 32 batch groups of 16 rows
#define BPG 8           // blocks per group, 128 neurons each

typedef int   v4i __attribute__((ext_vector_type(4)));
typedef float v4f __attribute__((ext_vector_type(4)));
typedef short v8s __attribute__((ext_vector_type(8)));

// ---- ws layout (bytes) ----
#define SLOTC_OFF  8192     // max|W_clf| bits
#define ROWMAX_OFF 9216     // per-row max|W_res[n][:]|, 1024 floats
#define MASK_OFF   16384    // L2 fast-path masks: 2 par x 32 g x 16 b x 64 prod x 4 B = 256 KB
#define MASKG_OFF  278528   // agent-scope backstop masks, same layout: 256 KB
#define WQF_OFF    540672   // W_res int8, MFMA-fragment order: 1 MB
#define WCF_OFF    1589248  // W_clf int8 fragment tile: 16 KB
#define LDS_BYTES  (131072 + 16*1040 + 1024 + 8192)  // B slice + A + xA + redC

__global__ __launch_bounds__(256) void maxabs_kernel(const float* __restrict__ W,
                                                     int n, unsigned* __restrict__ slot) {
    unsigned m = 0u;
    for (int i = blockIdx.x * 256 + threadIdx.x; i < n; i += gridDim.x * 256)
        m = max(m, __float_as_uint(W[i]) & 0x7fffffffu);
#pragma unroll
    for (int off = 32; off >= 1; off >>= 1)
        m = max(m, (unsigned)__shfl_xor((int)m, off, 64));
    if ((threadIdx.x & 63) == 0) atomicMax(slot, m);
}

// per-row max|W_res[n][:]| — one wave per row, plain store (deterministic)
__global__ __launch_bounds__(256) void rowmax_kernel(const float* __restrict__ W,
                                                     float* __restrict__ rowmax) {
    const int row = blockIdx.x * 4 + ((int)threadIdx.x >> 6);
    const int lane = threadIdx.x & 63;
    float m = 0.f;
    for (int j = lane; j < NRES; j += 64) m = fmaxf(m, fabsf(W[row * NRES + j]));
#pragma unroll
    for (int off = 32; off >= 1; off >>= 1) m = fmaxf(m, __shfl_xor(m, off, 64));
    if (lane == 0) rowmax[row] = m;
}

// W_res -> signed-int8 (PER-ROW scale) in MFMA B-fragment order:
// dword o4: bl=o4>>15, wv=(o4>>12)&7, kt=(o4>>8)&15, L=(o4>>2)&63, i0=(o4&3)*4
// n = bl*128+wv*16+(L&15); k = kt*64+(L>>4)*16+i0..+3
__global__ __launch_bounds__(256) void quant_res(const float* __restrict__ W,
                                                 const float* __restrict__ rowmax,
                                                 unsigned* __restrict__ dst) {
    const int o4 = blockIdx.x * 256 + threadIdx.x;
    const int bl = o4 >> 15, wv = (o4 >> 12) & 7, kt = (o4 >> 8) & 15;
    const int L = (o4 >> 2) & 63, i0 = (o4 & 3) * 4;
    const int n = bl * 128 + wv * 16 + (L & 15);
    const int k = kt * 64 + (L >> 4) * 16 + i0;
    const float inv = 127.0f / rowmax[n];
    unsigned dw = 0;
#pragma unroll
    for (int j = 0; j < 4; ++j) {
        float q = rintf(W[n * NRES + k + j] * inv);
        q = fminf(fmaxf(q, -127.f), 127.f);
        dw |= ((unsigned)((int)q & 0xff)) << (8 * j);
    }
    dst[o4] = dw;
}

// W_clf -> int8 fragment tile (16 cols, cls>=10 zero): 4096 dwords
__global__ __launch_bounds__(256) void quant_clf(const float* __restrict__ W,
                                                 const unsigned* __restrict__ slot,
                                                 unsigned* __restrict__ dst) {
    const int o4 = blockIdx.x * 256 + threadIdx.x;
    const int kt = (o4 >> 8) & 15, L = (o4 >> 2) & 63, i0 = (o4 & 3) * 4;
    const int cls = L & 15;
    const int k = kt * 64 + (L >> 4) * 16 + i0;
    const float inv = 127.0f / __uint_as_float(*slot);
    unsigned dw = 0;
    if (cls < NCLS) {
#pragma unroll
        for (int j = 0; j < 4; ++j) {
            float q = rintf(W[cls * NRES + k + j] * inv);
            q = fminf(fmaxf(q, -127.f), 127.f);
            dw |= ((unsigned)((int)q & 0xff)) << (8 * j);
        }
    }
    dst[o4] = dw;
}

__device__ __forceinline__ unsigned short f2bf(float f) {
    unsigned u = __float_as_uint(f);
    return (unsigned short)((u + 0x7fffu + ((u >> 16) & 1u)) >> 16);
}

// Hybrid tagged-mask poll. Fast path: sc0 (L1-bypass) load of the plain-store
// buffer -> served by the shared per-XCD L2 when producer is co-located
// (~200 cy RTT). Backstop: agent-scope load of the write-through buffer ->
// correct under ANY workgroup->XCD placement (this is exactly the old path).
// Tags self-validate the data, so either path may satisfy the poll.
__device__ __forceinline__ unsigned hybrid_poll(const unsigned long long* mpL,
                                                const unsigned long long* mpG,
                                                unsigned want) {
    unsigned lo, hi;
    int tries = 0;
    for (;;) {
        unsigned long long u;
        if ((tries < 6) || (tries & 1)) {
            asm volatile("global_load_dwordx2 %0, %1, off sc0\n\ts_waitcnt vmcnt(0)"
                         : "=v"(u) : "v"(mpL) : "memory");
        } else {
            u = __hip_atomic_load(mpG, __ATOMIC_RELAXED, __HIP_MEMORY_SCOPE_AGENT);
        }
        lo = (unsigned)u; hi = (unsigned)(u >> 32);
        if (((lo >> 16) == want) & ((hi >> 16) == want)) break;
        if (tries >= 6) __builtin_amdgcn_s_sleep(1);
        ++tries;
    }
    return (lo & 0xffffu) | ((hi & 0xffffu) << 16);
}

// ---------------------------------------------------------------------------
// 256 blocks x 512 threads (1/CU). Block = (group g, slot bl): 16 batch rows
// x 128 neurons, int8 W slice LDS-resident. Structure identical to the
// verified 5.14 ms kernel EXCEPT the mask transport: producers DUAL-PUBLISH
// each tagged mask dword (plain write-through store to maskL + agent-scope
// store to maskG); consumers hybrid-poll (sc0/L2 fast path, agent backstop).
// Group members share q%8 under round-robin dispatch -> same XCD -> the
// exchange resolves in local L2 instead of a fabric/L3 round trip.
// Numerics bit-identical (absmax must be exactly 32).
// ---------------------------------------------------------------------------
__global__ __launch_bounds__(512, 1) void reservoir_mfma(
    const float* __restrict__ x, const float* __restrict__ W_in,
    unsigned char* __restrict__ ws, float* __restrict__ out)
{
    // XCD co-location: 8 blocks of a group share q%8 (dispatch heuristic).
    const int q   = (int)blockIdx.x;
    const int g   = (q & 7) * 4 + ((q >> 3) & 3);
    const int bl  = q >> 5;
    const int tid = (int)threadIdx.x;
    const int L    = tid & 63;
    const int wv   = tid >> 6;     // 0..7
    const int col  = L & 15;       // MFMA n-col (neuron/cls)
    const int rowq = L >> 4;       // batch quad

    extern __shared__ char lds[];
    char* B_lds = lds;                                   // 131072 B
    char* A_lds = lds + 131072;                          // 16 x 1040 B
    unsigned short* xA = (unsigned short*)(lds + 131072 + 16 * 1040);  // 16x32 bf16
    char* redC = lds + 131072 + 16 * 1040 + 1024;        // 8 KB clf partials

    const float* rowmax = (const float*)(ws + ROWMAX_OFF);
    const float cscale = __uint_as_float(*(const unsigned*)(ws + SLOTC_OFF)) * (1.0f / 127.0f);
    unsigned char* maskL = ws + MASK_OFF;
    unsigned char* maskG = ws + MASKG_OFF;
    const unsigned char* wqf = ws + WQF_OFF;
    const unsigned char* wcf = ws + WCF_OFF;

    const int nn = bl * 128 + wv * 16 + col;             // my output neuron
    const float dscale = rowmax[nn] * (1.0f / 127.0f);
    const bool clfBlk = (bl == 0);

    // ---- load my 128 KB weight slice into LDS
    {
        const v4i* src = (const v4i*)(wqf + (size_t)bl * 131072);
        v4i* dst = (v4i*)B_lds;
        for (int i = tid; i < 8192; i += 512) dst[i] = src[i];
    }

    // ---- W_in hi/lo bf16 B-fragments
    v8s binf_h, binf_l;
#pragma unroll
    for (int i = 0; i < 8; ++i) {
        const int c = (rowq * 8 + i) & 15;
        const float w = W_in[nn * CIN + c];
        const unsigned short h = f2bf(w);
        const float wl = w - __uint_as_float((unsigned)h << 16);
        binf_h[i] = (short)h;
        binf_l[i] = (short)f2bf(wl);
    }

    // ---- classifier fragments preloaded to registers (block 0: wave wv owns kt=2wv,2wv+1)
    v4i bcf0 = {0,0,0,0}, bcf1 = {0,0,0,0};
    if (clfBlk) {
        bcf0 = *(const v4i*)(wcf + (2 * wv + 0) * 1024 + L * 16);
        bcf1 = *(const v4i*)(wcf + (2 * wv + 1) * 1024 + L * 16);
    }

    float v[4]  = {0.f, 0.f, 0.f, 0.f};
    int   accv[4] = {0, 0, 0, 0};
    float vc[4] = {0.f, 0.f, 0.f, 0.f};   // live on block0/wave0
    int   accc[4] = {0, 0, 0, 0};

    const int mb = tid >> 5, mseg = tid & 31;   // my mask-poll / A-build slot
    const size_t moff0 = (size_t)((0 * NGROUP + g) * 16 + mb) * 256 + mseg * 8;
    const size_t moff1 = (size_t)((1 * NGROUP + g) * 16 + mb) * 256 + mseg * 8;
    const unsigned long long* mL0 = (const unsigned long long*)(maskL + moff0);
    const unsigned long long* mL1 = (const unsigned long long*)(maskL + moff1);
    const unsigned long long* mG0 = (const unsigned long long*)(maskG + moff0);
    const unsigned long long* mG1 = (const unsigned long long*)(maskG + moff1);

    __syncthreads();

    for (int t = 0; t < TSTEPS; ++t) {
        // x_t load issued before the poll
        float xval = 0.f;
        if (tid < 256) {
            const int b = tid >> 4, c = tid & 15;
            xval = x[((size_t)(g * 16 + b) * CIN + c) * TSTEPS + t];
        }

        if (t > 0) {
            // ---- hybrid-poll tagged masks of step t-1 (parity (t-1)&1), expand to A
            const int pp = (t - 1) & 1;
            const unsigned m = hybrid_poll(pp ? mL1 : mL0, pp ? mG1 : mG0, (unsigned)t);
            unsigned w[8];
#pragma unroll
            for (int d = 0; d < 8; ++d) {
                const unsigned mm = m >> (4 * d);
                w[d] = (mm & 1u) | ((mm & 2u) << 7) | ((mm & 4u) << 14) | ((mm & 8u) << 21);
            }
            v4i* dst = (v4i*)(A_lds + mb * 1040 + mseg * 32);
            dst[0] = *(v4i*)&w[0];
            dst[1] = *(v4i*)&w[4];
        }
        // ---- stage x_t hi/lo
        if (tid < 256) {
            const int b = tid >> 4, c = tid & 15;
            const unsigned short h = f2bf(xval);
            const float lo2 = xval - __uint_as_float((unsigned)h << 16);
            xA[b * 32 + c] = h;
            xA[b * 32 + 16 + c] = f2bf(lo2);
        }
        __syncthreads();   // S2: A + xA ready

        // ---- input projection: (xh+xl).(Wh+Wl), 2 chained bf16 MFMAs
        v4f Din;
        {
            const v8s xa = *(const v8s*)((const char*)xA + col * 64 + rowq * 16);
            v4f z = {0.f, 0.f, 0.f, 0.f};
            const v4f D1 = __builtin_amdgcn_mfma_f32_16x16x32_bf16(xa, binf_h, z, 0, 0, 0);
            Din = __builtin_amdgcn_mfma_f32_16x16x32_bf16(xa, binf_l, D1, 0, 0, 0);
        }

        // ---- recurrent: 16 x mfma_i32_16x16x64_i8, 2 independent chains (exact)
        v4i Drec = {0, 0, 0, 0};
        if (t > 0) {
            const char* Bb = B_lds + wv * 16384;
            const char* Ab = A_lds + col * 1040 + rowq * 16;
            v4i Dr0 = {0,0,0,0}, Dr1 = {0,0,0,0};
#pragma unroll 4
            for (int kt = 0; kt < 16; kt += 2) {
                const v4i a0 = *(const v4i*)(Ab + kt * 64);
                const v4i b0 = *(const v4i*)(Bb + kt * 1024 + L * 16);
                const v4i a1 = *(const v4i*)(Ab + (kt + 1) * 64);
                const v4i b1 = *(const v4i*)(Bb + (kt + 1) * 1024 + L * 16);
                Dr0 = __builtin_amdgcn_mfma_i32_16x16x64_i8(a0, b0, Dr0, 0, 0, 0);
                Dr1 = __builtin_amdgcn_mfma_i32_16x16x64_i8(a1, b1, Dr1, 0, 0, 0);
            }
#pragma unroll
            for (int r = 0; r < 4; ++r) Drec[r] = Dr0[r] + Dr1[r];
        }

        // ---- classifier partials (block 0, spread: wave wv does kt=2wv,2wv+1)
        if (clfBlk && t > 0) {
            const char* Ab = A_lds + col * 1040 + rowq * 16;
            v4i Dc = {0, 0, 0, 0};
            const v4i a0 = *(const v4i*)(Ab + (2 * wv + 0) * 64);
            const v4i a1 = *(const v4i*)(Ab + (2 * wv + 1) * 64);
            Dc = __builtin_amdgcn_mfma_i32_16x16x64_i8(a0, bcf0, Dc, 0, 0, 0);
            Dc = __builtin_amdgcn_mfma_i32_16x16x64_i8(a1, bcf1, Dc, 0, 0, 0);
            *(v4i*)(redC + wv * 1024 + L * 16) = Dc;
        }
        __syncthreads();   // S3: A consumed; redC ready

        // ---- LIF + spikes + ballots
        unsigned long long bal0, bal1, bal2, bal3;
        {
            float vn; int s;
            vn = ALPHA * v[0] + Din[0] + dscale * (float)Drec[0];
            s = (vn >= THRESH); accv[0] += s; v[0] = s ? 0.f : vn; bal0 = __ballot(s);
            vn = ALPHA * v[1] + Din[1] + dscale * (float)Drec[1];
            s = (vn >= THRESH); accv[1] += s; v[1] = s ? 0.f : vn; bal1 = __ballot(s);
            vn = ALPHA * v[2] + Din[2] + dscale * (float)Drec[2];
            s = (vn >= THRESH); accv[2] += s; v[2] = s ? 0.f : vn; bal2 = __ballot(s);
            vn = ALPHA * v[3] + Din[3] + dscale * (float)Drec[3];
            s = (vn >= THRESH); accv[3] += s; v[3] = s ? 0.f : vn; bal3 = __ballot(s);
        }

        // ---- dual-publish tagged mask dword (tag = t+1), lanes 0..15
        {
            const int p = t & 1;
            if (L < 16) {
                const int b = L;
                const unsigned long long bb = (b & 2) ? ((b & 1) ? bal3 : bal2)
                                                      : ((b & 1) ? bal1 : bal0);
                const unsigned fld = (unsigned)((bb >> ((b >> 2) * 16)) & 0xFFFFu);
                const unsigned val = ((unsigned)(t + 1) << 16) | fld;
                const size_t off = (size_t)((p * NGROUP + g) * 16 + b) * 256
                                 + (bl * 8 + wv) * 4;
                unsigned* mpL = (unsigned*)(maskL + off);
                unsigned* mpG = (unsigned*)(maskG + off);
                // L2 fast path: plain write-through store (visible to same-XCD
                // sc0 pollers in ~L2 latency)
                asm volatile("global_store_dword %0, %1, off"
                             :: "v"(mpL), "v"(val) : "memory");
                // agent backstop: correct under any placement
                __hip_atomic_store(mpG, val, __ATOMIC_RELAXED, __HIP_MEMORY_SCOPE_AGENT);
            }
        }

        // ---- classifier reduce + LIF (block 0, wave 0; reads redC after S3)
        if (clfBlk && wv == 0 && t > 0) {
            v4i c0 = *(const v4i*)(redC + 0 * 1024 + L * 16);
#pragma unroll
            for (int jj = 1; jj < 8; ++jj) {
                const v4i cj = *(const v4i*)(redC + jj * 1024 + L * 16);
#pragma unroll
                for (int r = 0; r < 4; ++r) c0[r] += cj[r];
            }
#pragma unroll
            for (int r = 0; r < 4; ++r) {
                const float vcn = ALPHA * vc[r] + cscale * (float)c0[r];
                const int sc = (vcn >= THRESH);
                accc[r] += sc;
                vc[r] = sc ? 0.f : vcn;
            }
        }
        // no end-of-loop barrier: each thread's next-step poll gates its own
        // A-build write; S2/S3 order all LDS hazards (see analysis).
    }

    // ---- epilogue: classifier flush with s_{T-1} (parity 1, tag TSTEPS)
    if (clfBlk) {
        {
            const unsigned m = hybrid_poll(mL1, mG1, (unsigned)TSTEPS);
            unsigned w[8];
#pragma unroll
            for (int d = 0; d < 8; ++d) {
                const unsigned mm = m >> (4 * d);
                w[d] = (mm & 1u) | ((mm & 2u) << 7) | ((mm & 4u) << 14) | ((mm & 8u) << 21);
            }
            v4i* dst = (v4i*)(A_lds + mb * 1040 + mseg * 32);
            dst[0] = *(v4i*)&w[0];
            dst[1] = *(v4i*)&w[4];
        }
        __syncthreads();
        {
            const char* Ab = A_lds + col * 1040 + rowq * 16;
            v4i Dc = {0, 0, 0, 0};
            const v4i a0 = *(const v4i*)(Ab + (2 * wv + 0) * 64);
            const v4i a1 = *(const v4i*)(Ab + (2 * wv + 1) * 64);
            Dc = __builtin_amdgcn_mfma_i32_16x16x64_i8(a0, bcf0, Dc, 0, 0, 0);
            Dc = __builtin_amdgcn_mfma_i32_16x16x64_i8(a1, bcf1, Dc, 0, 0, 0);
            *(v4i*)(redC + wv * 1024 + L * 16) = Dc;
        }
        __syncthreads();
        if (wv == 0 && col < NCLS) {
            v4i c0 = *(const v4i*)(redC + 0 * 1024 + L * 16);
#pragma unroll
            for (int jj = 1; jj < 8; ++jj) {
                const v4i cj = *(const v4i*)(redC + jj * 1024 + L * 16);
#pragma unroll
                for (int r = 0; r < 4; ++r) c0[r] += cj[r];
            }
#pragma unroll
            for (int r = 0; r < 4; ++r) {
                const float vcn = ALPHA * vc[r] + cscale * (float)c0[r];
                const int sc = (vcn >= THRESH);
                out[(size_t)(g * 16 + rowq * 4 + r) * NCLS + col] = (float)(accc[r] + sc);
            }
        }
    }
    {
#pragma unroll
        for (int r = 0; r < 4; ++r) {
            const int bglob = g * 16 + rowq * 4 + r;
            out[BATCH * NCLS + (size_t)bglob * NRES + nn] = (float)accv[r];
        }
    }
}

extern "C" void kernel_launch(void* const* d_in, const int* in_sizes, int n_in,
                              void* d_out, int out_size, void* d_ws, size_t ws_size,
                              hipStream_t stream) {
    (void)in_sizes; (void)n_in; (void)out_size; (void)ws_size;
    const float* x     = (const float*)d_in[0];
    const float* W_in  = (const float*)d_in[1];
    const float* W_res = (const float*)d_in[2];
    const float* W_clf = (const float*)d_in[3];
    float* out = (float*)d_out;
    unsigned char* ws = (unsigned char*)d_ws;

    // zero: scale slots + rowmax + BOTH tagged-mask regions (tags 0 never match)
    hipMemsetAsync(ws, 0, MASK_OFF + 2 * 262144, stream);
    rowmax_kernel<<<256, 256, 0, stream>>>(W_res, (float*)(ws + ROWMAX_OFF));
    maxabs_kernel<<<16, 256, 0, stream>>>(W_clf, NCLS * NRES, (unsigned*)(ws + SLOTC_OFF));
    quant_res<<<1024, 256, 0, stream>>>(W_res, (const float*)(ws + ROWMAX_OFF),
                                        (unsigned*)(ws + WQF_OFF));
    quant_clf<<<16, 256, 0, stream>>>(W_clf, (const unsigned*)(ws + SLOTC_OFF),
                                      (unsigned*)(ws + WCF_OFF));
    reservoir_mfma<<<NGROUP * BPG, 512, LDS_BYTES, stream>>>(x, W_in, ws, out);
}